// Round 6
// baseline (126.787 us; speedup 1.0000x reference)
//
#include <hip/hip_runtime.h>

// DifferentiableRGBtoVel: image (4,3,512,512) fp32, cmap (256,3) fp32, v_i (256) fp32
// out velocities (4,512,512) fp32.
//
// logit_k = -dist_k^2/(T*ln2) = A_k·p + B_k + C_p (exp2 form), A_k=2*K2*c_k,
// B_k=-K2*|c_k|^2, C_p=-K2*|p|^2, K2=1/(0.01*ln2)=144.27. All logits <= 0;
// C_p cancels in the softmax ratio (it only keeps exp2 in range).
//
// v6: v5's verified poly-exp2 numerics (rintf split + degree-3 minimax,
// absmax 0.0039 = same floor as hw v_exp_f32) with two fixes:
//  - the scale step is a single HW v_ldexp_f32 via inline asm. v5's
//    __has_builtin(__builtin_amdgcn_ldexpf) fell through to library ldexpf()
//    (~10 insts of edge-case handling x2/pair = +33 cyc/pair, 48.8->76.9us).
//    v_ldexp_f32 underflows to zero for large negative n, so no clamp needed
//    (max logit magnitude ~433; nearest-color weight >= 2^-30 keeps sum > 0).
//  - 4 pixels per lane: the unpackable scalar trio (rndne/cvt/ldexp) and the
//    loop/s_load overhead amortize over 2x the cells.
// Budget: 20 pk + 12 scalar VALU per k-iter = 64 issue-cyc per 4 cells.

typedef float v2f __attribute__((ext_vector_type(2)));

#define HWSZ 262144              // 512*512
#define NPIX 1048576             // 4*512*512
#define K2F  144.2695040888963f  // 1/(0.01*ln2)

__device__ __forceinline__ float ldexp_hw(float x, int n) {
  float r;
  asm("v_ldexp_f32 %0, %1, %2" : "=v"(r) : "v"(x), "v"(n));
  return r;
}

__global__ __launch_bounds__(256) void rgb2vel_prep(
    const float* __restrict__ cmap, const float* __restrict__ v_i,
    float4* __restrict__ ab, float* __restrict__ vv) {
  int k = threadIdx.x;  // 256 threads, 1 block
  float cx = cmap[k * 3 + 0];
  float cy = cmap[k * 3 + 1];
  float cz = cmap[k * 3 + 2];
  float4 r;
  r.x = 2.0f * K2F * cx;
  r.y = 2.0f * K2F * cy;
  r.z = 2.0f * K2F * cz;
  r.w = -K2F * (cx * cx + cy * cy + cz * cz);
  ab[k] = r;
  vv[k] = v_i[k];
}

__global__ __launch_bounds__(256) void rgb2vel_main(
    const float* __restrict__ img, const float4* __restrict__ ab,
    const float* __restrict__ vv, float* __restrict__ out) {
  int t = blockIdx.x * 256 + threadIdx.x;  // quad index, [0, NPIX/4)
  int n = t >> 16;                         // image index (65536 quads/image)
  int hw4 = (t & 65535) << 2;              // first pixel of the quad
  const float* base = img + (size_t)n * 3 * HWSZ + hw4;
  v2f px0 = {base[0], base[1]};
  v2f px1 = {base[2], base[3]};
  v2f py0 = {base[HWSZ], base[HWSZ + 1]};
  v2f py1 = {base[HWSZ + 2], base[HWSZ + 3]};
  v2f pz0 = {base[2 * HWSZ], base[2 * HWSZ + 1]};
  v2f pz1 = {base[2 * HWSZ + 2], base[2 * HWSZ + 3]};

  // cp = -K2*|p|^2 per pixel (packed)
  v2f mk2 = {-K2F, -K2F};
  v2f cp0 = __builtin_elementwise_fma(
                px0, px0, __builtin_elementwise_fma(py0, py0, pz0 * pz0)) *
            mk2;
  v2f cp1 = __builtin_elementwise_fma(
                px1, px1, __builtin_elementwise_fma(py1, py1, pz1 * pz1)) *
            mk2;

  const v2f C3 = {0.0555041f, 0.0555041f};
  const v2f C2 = {0.2426310f, 0.2426310f};
  const v2f C1 = {0.6931472f, 0.6931472f};
  const v2f C0 = {0.9999249f, 0.9999249f};

  v2f s0 = {0.0f, 0.0f}, s1 = {0.0f, 0.0f};
  v2f sv0 = {0.0f, 0.0f}, sv1 = {0.0f, 0.0f};
#pragma unroll 16
  for (int k = 0; k < 256; ++k) {
    float4 c = ab[k];  // uniform index -> s_load_dwordx4
    v2f cx = {c.x, c.x};
    v2f cy = {c.y, c.y};
    v2f cz = {c.z, c.z};
    v2f cw = {c.w, c.w};
    // logit = A·p + B + cp   (4 pk ops per half); always <= ~0
    v2f a0 = __builtin_elementwise_fma(
        cx, px0,
        __builtin_elementwise_fma(
            cy, py0, __builtin_elementwise_fma(cz, pz0, cw + cp0)));
    v2f a1 = __builtin_elementwise_fma(
        cx, px1,
        __builtin_elementwise_fma(
            cy, py1, __builtin_elementwise_fma(cz, pz1, cw + cp1)));
    // split: n = rint(a) (v_rndne_f32), r = a - n in [-0.5, 0.5]
    v2f nf0, nf1;
    nf0.x = __builtin_rintf(a0.x);
    nf0.y = __builtin_rintf(a0.y);
    nf1.x = __builtin_rintf(a1.x);
    nf1.y = __builtin_rintf(a1.y);
    v2f r0 = a0 - nf0;
    v2f r1 = a1 - nf1;
    // 2^r polynomial (3 pk fma per half, rel err ~1.2e-4)
    v2f p0 = __builtin_elementwise_fma(
        __builtin_elementwise_fma(__builtin_elementwise_fma(C3, r0, C2), r0,
                                  C1),
        r0, C0);
    v2f p1 = __builtin_elementwise_fma(
        __builtin_elementwise_fma(__builtin_elementwise_fma(C3, r1, C2), r1,
                                  C1),
        r1, C0);
    // scale by 2^n: one v_cvt_i32_f32 + one v_ldexp_f32 per element
    v2f w0, w1;
    w0.x = ldexp_hw(p0.x, (int)nf0.x);
    w0.y = ldexp_hw(p0.y, (int)nf0.y);
    w1.x = ldexp_hw(p1.x, (int)nf1.x);
    w1.y = ldexp_hw(p1.y, (int)nf1.y);
    s0 = s0 + w0;
    s1 = s1 + w1;
    float vk = vv[k];  // uniform -> s_load
    v2f vkv = {vk, vk};
    sv0 = __builtin_elementwise_fma(w0, vkv, sv0);
    sv1 = __builtin_elementwise_fma(w1, vkv, sv1);
  }
  size_t o = (size_t)4 * t;
  out[o + 0] = sv0.x / s0.x;
  out[o + 1] = sv0.y / s0.y;
  out[o + 2] = sv1.x / s1.x;
  out[o + 3] = sv1.y / s1.y;
}

extern "C" void kernel_launch(void* const* d_in, const int* in_sizes, int n_in,
                              void* d_out, int out_size, void* d_ws, size_t ws_size,
                              hipStream_t stream) {
  const float* image = (const float*)d_in[0];  // (4,3,512,512)
  const float* cmap  = (const float*)d_in[1];  // (256,3)
  const float* v_i   = (const float*)d_in[2];  // (256,)
  float* out = (float*)d_out;                  // (4,512,512)

  float4* ab = (float4*)d_ws;                      // 256 * 16 B
  float*  vv = (float*)((char*)d_ws + 256 * 16);   // 256 * 4 B

  rgb2vel_prep<<<1, 256, 0, stream>>>(cmap, v_i, ab, vv);
  rgb2vel_main<<<NPIX / 4 / 256, 256, 0, stream>>>(image, ab, vv, out);
}